// Round 5
// baseline (550.783 us; speedup 1.0000x reference)
//
#include <hip/hip_runtime.h>
#include <cstdint>
#include <cstddef>

#define DEVI __device__ __forceinline__

typedef __attribute__((ext_vector_type(8))) short bf16x8;
typedef __attribute__((ext_vector_type(4))) float f32x4;

DEVI unsigned short f2bf(float f) {
  unsigned int u = __float_as_uint(f);
  u += 0x7fffu + ((u >> 16) & 1u);   // RNE
  return (unsigned short)(u >> 16);
}
DEVI float bf2f(unsigned int us) { return __uint_as_float(us << 16); }

DEVI void gld_lds16(const void* g, void* l) {
  __builtin_amdgcn_global_load_lds(
      (const __attribute__((address_space(1))) void*)g,
      (__attribute__((address_space(3))) void*)l, 16, 0, 0);
}

// ---------------- fp32 -> bf16 elementwise ----------------
__global__ __launch_bounds__(256) void k_conv(const float* __restrict__ in,
                                              short* __restrict__ out, int n4) {
  int i = blockIdx.x * 256 + threadIdx.x;
  if (i >= n4) return;
  float4 v = reinterpret_cast<const float4*>(in)[i];
  uint2 o;
  o.x = (unsigned)f2bf(v.x) | ((unsigned)f2bf(v.y) << 16);
  o.y = (unsigned)f2bf(v.z) | ((unsigned)f2bf(v.w) << 16);
  reinterpret_cast<uint2*>(out)[i] = o;
}

// ---------------- fp32 [R][C] -> bf16 [C][R] transpose ----------------
__global__ __launch_bounds__(256) void k_transpose(const float* __restrict__ in,
                                                   short* __restrict__ out,
                                                   int R, int Cc) {
  __shared__ short tile[64][66];
  int tcols = Cc >> 6;
  int tb = blockIdx.x % tcols;
  int rb = blockIdx.x / tcols;
  int tid = threadIdx.x;
#pragma unroll
  for (int rep = 0; rep < 16; ++rep) {
    int idx = rep * 256 + tid;
    int r = idx >> 6, c = idx & 63;
    tile[r][c] = (short)f2bf(in[(size_t)(rb * 64 + r) * Cc + tb * 64 + c]);
  }
  __syncthreads();
#pragma unroll
  for (int rep = 0; rep < 16; ++rep) {
    int idx = rep * 256 + tid;
    int r = idx >> 6, c = idx & 63;
    out[(size_t)(tb * 64 + r) * R + rb * 64 + c] = tile[c][r];
  }
}

// ---------------- bf16 GEMM, B^T input: segment-pipelined ----------------
// BM=BN=256, BK=32, 512 thr (8 waves 2Mx4N), 4 LDS buffers (128KB).
// One SEGMENT = 2 K-tiles: {issue 16 gld_lds for tiles t+2,t+3 (their
// buffers' readers retired behind previous barrier -> race-free); then
// 2x(12 ds_read + 32 MFMA) with NO barriers/waits inside; then vmcnt(0)
// (cheap: loads had a full segment to land) + one s_barrier}.
// Granule-XOR swizzle (g ^ ((row>>1)&3)) via pre-swizzled global source.
template <typename OutT>
__global__ __launch_bounds__(512, 2) void k_gemm8(const short* __restrict__ A,
                                                  const short* __restrict__ BT,
                                                  OutT* __restrict__ C,
                                                  int M, int N, int K) {
  __shared__ short sA[4][8192];   // [buf][256 rows][32 k], swizzled granules
  __shared__ short sB[4][8192];
  const int tid = threadIdx.x;
  const int wv = tid >> 6, lane = tid & 63;
  const int l16 = lane & 15, lhi = lane >> 4;
  const int wr = wv >> 2, wc = wv & 3;          // wave grid 2M x 4N
  const int bm = blockIdx.x * 256, bn = blockIdx.y * 256;
  const int srow0 = wv * 16 + (lane >> 2);      // staging row within 128-half
  const int sgs = lane & 3;                     // stored granule
  const int NT = K >> 5;                        // BK=32 tiles (NT even)

  auto stageA = [&](int kt, int b) {
#pragma unroll
    for (int j = 0; j < 2; ++j) {
      int row = j * 128 + srow0;
      int g = sgs ^ ((row >> 1) & 3);           // logical granule for this slot
      gld_lds16(A + (size_t)(bm + row) * K + kt + g * 8,
                &sA[b][j * 4096 + wv * 512]);   // wave-uniform base + lane*16B
    }
  };
  auto stageB = [&](int kt, int b) {
#pragma unroll
    for (int j = 0; j < 2; ++j) {
      int row = j * 128 + srow0;
      int g = sgs ^ ((row >> 1) & 3);
      gld_lds16(BT + (size_t)(bn + row) * K + kt + g * 8,
                &sB[b][j * 4096 + wv * 512]);
    }
  };

  f32x4 acc[8][4] = {};

  // prologue: stage tiles 0,1; publish
  stageA(0, 0); stageB(0, 0);
  stageA(32, 1); stageB(32, 1);
  asm volatile("s_waitcnt vmcnt(0)" ::: "memory");
  __builtin_amdgcn_s_barrier();

  for (int t = 0; t < NT; t += 2) {
    // issue-early staging for tiles t+2, t+3 (buffers (t+2)&3, (t+3)&3)
    if (t + 2 < NT) { stageA((t + 2) * 32, (t + 2) & 3);
                      stageB((t + 2) * 32, (t + 2) & 3); }
    if (t + 3 < NT) { stageA((t + 3) * 32, (t + 3) & 3);
                      stageB((t + 3) * 32, (t + 3) & 3); }
    __builtin_amdgcn_sched_barrier(0);           // pin stage-issue first
    // compute tiles t, t+1 — long barrier-free region
#pragma unroll
    for (int u = 0; u < 2; ++u) {
      const short* bufA = sA[(t + u) & 3];
      const short* bufB = sB[(t + u) & 3];
      bf16x8 bfr[4], af[8];
#pragma unroll
      for (int n = 0; n < 4; ++n) {
        int row = wc * 64 + n * 16 + l16;
        bfr[n] = *(const bf16x8*)&bufB[row * 32 + ((lhi ^ ((row >> 1) & 3)) << 3)];
      }
#pragma unroll
      for (int m = 0; m < 8; ++m) {
        int row = wr * 128 + m * 16 + l16;
        af[m] = *(const bf16x8*)&bufA[row * 32 + ((lhi ^ ((row >> 1) & 3)) << 3)];
      }
      __builtin_amdgcn_s_setprio(1);
#pragma unroll
      for (int m = 0; m < 8; ++m)
#pragma unroll
        for (int n = 0; n < 4; ++n)
          acc[m][n] = __builtin_amdgcn_mfma_f32_16x16x32_bf16(af[m], bfr[n],
                                                              acc[m][n], 0, 0, 0);
      __builtin_amdgcn_s_setprio(0);
    }
    asm volatile("s_waitcnt vmcnt(0)" ::: "memory");  // staged loads landed
    __builtin_amdgcn_s_barrier();                     // publish t+2, t+3
  }

#pragma unroll
  for (int m = 0; m < 8; ++m) {
#pragma unroll
    for (int n = 0; n < 4; ++n) {
      int col = bn + wc * 64 + n * 16 + l16;
#pragma unroll
      for (int r = 0; r < 4; ++r) {
        int row = bm + wr * 128 + m * 16 + lhi * 4 + r;
        if constexpr (sizeof(OutT) == 2)
          C[(size_t)row * N + col] = (OutT)f2bf(acc[m][n][r]);
        else
          C[(size_t)row * N + col] = acc[m][n][r];
      }
    }
  }
}

// ---------------- RoPE: qkv -> Qr,Kr in [B,H,T,128] bf16 ----------------
// Q additionally pre-scaled by 1/sqrt(hd) * log2(e) so QK^T lands in exp2 domain.
__global__ __launch_bounds__(256) void k_rope(const short* __restrict__ qkv,
                                              const float* __restrict__ cosb,
                                              const float* __restrict__ sinb,
                                              short* __restrict__ Qr,
                                              short* __restrict__ Kr) {
  const float kC = 0.08838834764831845f * 1.44269504088896340f;
  int gid = blockIdx.x * 4 + (threadIdx.x >> 6);  // (b*T+t)*H + h
  int lane = threadIdx.x & 63;                    // pair index 0..63
  int h = gid & 15;
  int bt = gid >> 4;
  int t = bt & 2047;
  int b = bt >> 11;
  float c = cosb[t * 64 + lane];
  float s = sinb[t * 64 + lane];
  size_t qidx = (size_t)bt * 6144 + h * 128 + 2 * lane;
  size_t oidx = ((size_t)(b * 16 + h) * 2048 + t) * 128 + 2 * lane;
  unsigned int qp = *reinterpret_cast<const unsigned int*>(qkv + qidx);
  {
    float x1 = bf2f(qp & 0xffffu), x2 = bf2f(qp >> 16);
    unsigned int o = (unsigned)f2bf((x1 * c - x2 * s) * kC) |
                     ((unsigned)f2bf((x1 * s + x2 * c) * kC) << 16);
    *reinterpret_cast<unsigned int*>(Qr + oidx) = o;
  }
  unsigned int kp = *reinterpret_cast<const unsigned int*>(qkv + qidx + 2048);
  {
    float x1 = bf2f(kp & 0xffffu), x2 = bf2f(kp >> 16);
    unsigned int o = (unsigned)f2bf(x1 * c - x2 * s) |
                     ((unsigned)f2bf(x1 * s + x2 * c) << 16);
    *reinterpret_cast<unsigned int*>(Kr + oidx) = o;
  }
}

// ---------------- V transpose: qkv v-part -> VT [B,H,128,T] bf16 ----------------
__global__ __launch_bounds__(256) void k_vtrans(const short* __restrict__ qkv,
                                                short* __restrict__ VT) {
  __shared__ short tile[64][66];
  int bh = blockIdx.x;
  int t0 = blockIdx.y * 64;
  int d0 = blockIdx.z * 64;
  int b = bh >> 4, h = bh & 15;
  int tid = threadIdx.x;
#pragma unroll
  for (int rep = 0; rep < 16; ++rep) {
    int idx = rep * 256 + tid;
    int r = idx >> 6, c = idx & 63;
    tile[r][c] = qkv[(size_t)(b * 2048 + t0 + r) * 6144 + 4096 + h * 128 + d0 + c];
  }
  __syncthreads();
#pragma unroll
  for (int rep = 0; rep < 16; ++rep) {
    int idx = rep * 256 + tid;
    int r = idx >> 6, c = idx & 63;
    VT[(size_t)(bh * 128 + d0 + r) * 2048 + t0 + c] = tile[c][r];
  }
}

// ---------------- causal flash attention (v2) ----------------
__global__ __launch_bounds__(256) void k_attn(const short* __restrict__ Qr,
                                              const short* __restrict__ Kr,
                                              const short* __restrict__ VT,
                                              short* __restrict__ Y) {
  __shared__ short sK[2][64 * 128];
  __shared__ short sVT[2][128 * 64];
  __shared__ short sP[4][16 * 64];
  const int tid = threadIdx.x, wv = tid >> 6, lane = tid & 63;
  const int l8r = lane >> 3, l8c = lane & 7, l16 = lane & 15, lhi = lane >> 4;
  const int bid = blockIdx.x;
  const int pair = bid & 15, bh = bid >> 4;
  const size_t base = (size_t)bh * 2048 * 128;
  const int b = bh >> 4, h = bh & 15;

  const short ob = (short)0x3F80;                   // bf16 1.0
  const bf16x8 ones = {ob, ob, ob, ob, ob, ob, ob, ob};

  auto stage = [&](int kv0, int buf) {
#pragma unroll
    for (int rr = 0; rr < 4; ++rr) {
      int ch = rr * 4 + wv;
      {                                    // sK: row stride 256B, chunk = 4 rows
        int row = ch * 4 + lhi;
        int wch = l16 ^ (row & 7);         // inverse-swizzled source chunk
        gld_lds16(Kr + base + (size_t)(kv0 + row) * 128 + wch * 8,
                  &sK[buf][ch * 512]);
      }
      {                                    // sVT: row stride 128B, chunk = 8 rows
        int drow = ch * 8 + l8r;
        int wch = l8c ^ (drow & 7);
        gld_lds16(VT + base + (size_t)drow * 2048 + kv0 + wch * 8,
                  &sVT[buf][ch * 512]);
      }
    }
  };

  for (int half = 0; half < 2; ++half) {
    const int qt = half ? 31 - pair : pair;
    const int q0 = qt * 64;
    const int nt = qt + 1;

    bf16x8 qf[4];
    const int qrow = q0 + wv * 16 + l16;
#pragma unroll
    for (int ks = 0; ks < 4; ++ks)
      qf[ks] = *reinterpret_cast<const bf16x8*>(Qr + base + (size_t)qrow * 128 +
                                                ks * 32 + lhi * 8);

    f32x4 acc_o[8] = {};
    f32x4 acc_l = {};
    float m_run[4];
#pragma unroll
    for (int r = 0; r < 4; ++r) m_run[r] = -1e30f;

    stage(0, 0);
    __syncthreads();

    for (int it = 0; it < nt; ++it) {
      const int cur = it & 1;
      if (it + 1 < nt) stage((it + 1) * 64, cur ^ 1);   // prefetch next tile

      // S = Q K^T  (scores already in exp2 domain: kC folded into Q)
      f32x4 sacc[4] = {};
#pragma unroll
      for (int cf = 0; cf < 4; ++cf) {
        int krow = cf * 16 + l16;
#pragma unroll
        for (int ks = 0; ks < 4; ++ks) {
          int e = krow * 128 + ks * 32 + lhi * 8;
          bf16x8 kf = *reinterpret_cast<const bf16x8*>(
              &sK[cur][e ^ ((krow & 7) << 3)]);
          sacc[cf] = __builtin_amdgcn_mfma_f32_16x16x32_bf16(qf[ks], kf,
                                                             sacc[cf], 0, 0, 0);
        }
      }

      if (it == nt - 1) {                  // causal mask on diagonal tile
#pragma unroll
        for (int cf = 0; cf < 4; ++cf) {
          int col = cf * 16 + l16;
#pragma unroll
          for (int r = 0; r < 4; ++r)
            if (col > wv * 16 + lhi * 4 + r) sacc[cf][r] = -3e38f;
        }
      }

      // defer-max: slow path only when a row max grows past THR=8 (exp2-units)
      bool exceed = false;
#pragma unroll
      for (int cf = 0; cf < 4; ++cf)
#pragma unroll
        for (int r = 0; r < 4; ++r)
          exceed |= (sacc[cf][r] > m_run[r] + 8.f);

      if (__any(exceed)) {
        float resc[4];
#pragma unroll
        for (int r = 0; r < 4; ++r) {
          float mx = fmaxf(fmaxf(sacc[0][r], sacc[1][r]),
                           fmaxf(sacc[2][r], sacc[3][r]));
          mx = fmaxf(mx, __shfl_xor(mx, 1));
          mx = fmaxf(mx, __shfl_xor(mx, 2));
          mx = fmaxf(mx, __shfl_xor(mx, 4));
          mx = fmaxf(mx, __shfl_xor(mx, 8));
          float mnew = fmaxf(m_run[r], mx);
          resc[r] = exp2f(m_run[r] - mnew);
          m_run[r] = mnew;
        }
#pragma unroll
        for (int df = 0; df < 8; ++df)
#pragma unroll
          for (int r = 0; r < 4; ++r) acc_o[df][r] *= resc[r];
#pragma unroll
        for (int r = 0; r < 4; ++r) acc_l[r] *= resc[r];
      }

      // P = exp2(S - m), bf16, into per-wave swizzled LDS (A-frag reshape)
#pragma unroll
      for (int cf = 0; cf < 4; ++cf)
#pragma unroll
        for (int r = 0; r < 4; ++r) {
          float p = exp2f(sacc[cf][r] - m_run[r]);
          int prow = lhi * 4 + r;
          int e = prow * 64 + cf * 16 + l16;
          sP[wv][e ^ ((prow & 7) << 3)] = (short)f2bf(p);
        }

      // O += P V ; l += P * ones  (row-sum via MFMA, no shuffle reduce)
#pragma unroll
      for (int kk = 0; kk < 2; ++kk) {
        int e = l16 * 64 + kk * 32 + lhi * 8;
        bf16x8 pa = *reinterpret_cast<const bf16x8*>(
            &sP[wv][e ^ ((l16 & 7) << 3)]);
        acc_l = __builtin_amdgcn_mfma_f32_16x16x32_bf16(pa, ones, acc_l, 0, 0, 0);
#pragma unroll
        for (int df = 0; df < 8; ++df) {
          int vrow = df * 16 + l16;
          int ev = vrow * 64 + kk * 32 + lhi * 8;
          bf16x8 vb = *reinterpret_cast<const bf16x8*>(
              &sVT[cur][ev ^ ((vrow & 7) << 3)]);
          acc_o[df] = __builtin_amdgcn_mfma_f32_16x16x32_bf16(pa, vb,
                                                              acc_o[df], 0, 0, 0);
        }
      }
      __syncthreads();   // drains prefetch vmcnt + protects LDS buffers
    }

    float inv[4];
#pragma unroll
    for (int r = 0; r < 4; ++r) inv[r] = 1.f / acc_l[r];
#pragma unroll
    for (int df = 0; df < 8; ++df) {
      int col = h * 128 + df * 16 + l16;
#pragma unroll
      for (int r = 0; r < 4; ++r) {
        int row = q0 + wv * 16 + lhi * 4 + r;
        Y[((size_t)b * 2048 + row) * 2048 + col] =
            (short)f2bf(acc_o[df][r] * inv[r]);
      }
    }
  }
}

// ---------------- launch ----------------
extern "C" void kernel_launch(void* const* d_in, const int* in_sizes, int n_in,
                              void* d_out, int out_size, void* d_ws, size_t ws_size,
                              hipStream_t stream) {
  const float* x        = (const float*)d_in[0];
  const float* w_attn   = (const float*)d_in[1];
  const float* w_proj   = (const float*)d_in[2];
  const float* rope_cos = (const float*)d_in[3];
  const float* rope_sin = (const float*)d_in[4];

  char* ws = (char*)d_ws;                     // 256 MiB total layout
  short* xbf    = (short*)(ws);               // 33.5 MB  [8192][2048]
  short* wattnT = (short*)(ws + 33554432ull); // 25.2 MB  [6144][2048]
  short* wprojT = (short*)(ws + 58720256ull); //  8.4 MB  [2048][2048]
  short* qkv    = (short*)(ws + 67108864ull); // 100.7 MB [8192][6144]
  short* Y      = qkv;                        // alias dead q-region (33.5 MB)
  short* Qr     = (short*)(ws + 167772160ull);// 33.5 MB  [B,H,T,128]
  short* Kr     = (short*)(ws + 201326592ull);// 33.5 MB  [B,H,T,128]
  short* VT     = (short*)(ws + 234881024ull);// 33.5 MB  [B,H,128,T]

  k_conv<<<16384, 256, 0, stream>>>(x, xbf, 4194304);
  k_transpose<<<3072, 256, 0, stream>>>(w_attn, wattnT, 2048, 6144);
  k_transpose<<<1024, 256, 0, stream>>>(w_proj, wprojT, 2048, 2048);
  k_gemm8<short><<<dim3(32, 24), 512, 0, stream>>>(xbf, wattnT, qkv,
                                                   8192, 6144, 2048);
  k_rope<<<32768, 256, 0, stream>>>(qkv, rope_cos, rope_sin, Qr, Kr);
  k_vtrans<<<dim3(64, 32, 2), 256, 0, stream>>>(qkv, VT);
  k_attn<<<1024, 256, 0, stream>>>(Qr, Kr, VT, Y);
  k_gemm8<float><<<dim3(32, 8), 512, 0, stream>>>(Y, wprojT, (float*)d_out,
                                                  8192, 2048, 2048);
}

// Round 6
// 521.724 us; speedup vs baseline: 1.0557x; 1.0557x over previous
//
#include <hip/hip_runtime.h>
#include <cstdint>
#include <cstddef>

#define DEVI __device__ __forceinline__

typedef __attribute__((ext_vector_type(8))) short bf16x8;
typedef __attribute__((ext_vector_type(4))) float f32x4;

DEVI unsigned short f2bf(float f) {
  unsigned int u = __float_as_uint(f);
  u += 0x7fffu + ((u >> 16) & 1u);   // RNE
  return (unsigned short)(u >> 16);
}
DEVI float bf2f(unsigned int us) { return __uint_as_float(us << 16); }

DEVI void gld_lds16(const void* g, void* l) {
  __builtin_amdgcn_global_load_lds(
      (const __attribute__((address_space(1))) void*)g,
      (__attribute__((address_space(3))) void*)l, 16, 0, 0);
}

// ---------------- fp32 -> bf16 elementwise ----------------
__global__ __launch_bounds__(256) void k_conv(const float* __restrict__ in,
                                              short* __restrict__ out, int n4) {
  int i = blockIdx.x * 256 + threadIdx.x;
  if (i >= n4) return;
  float4 v = reinterpret_cast<const float4*>(in)[i];
  uint2 o;
  o.x = (unsigned)f2bf(v.x) | ((unsigned)f2bf(v.y) << 16);
  o.y = (unsigned)f2bf(v.z) | ((unsigned)f2bf(v.w) << 16);
  reinterpret_cast<uint2*>(out)[i] = o;
}

// ---------------- fp32 [R][C] -> bf16 [C][R] transpose ----------------
__global__ __launch_bounds__(256) void k_transpose(const float* __restrict__ in,
                                                   short* __restrict__ out,
                                                   int R, int Cc) {
  __shared__ short tile[64][66];
  int tcols = Cc >> 6;
  int tb = blockIdx.x % tcols;
  int rb = blockIdx.x / tcols;
  int tid = threadIdx.x;
#pragma unroll
  for (int rep = 0; rep < 16; ++rep) {
    int idx = rep * 256 + tid;
    int r = idx >> 6, c = idx & 63;
    tile[r][c] = (short)f2bf(in[(size_t)(rb * 64 + r) * Cc + tb * 64 + c]);
  }
  __syncthreads();
#pragma unroll
  for (int rep = 0; rep < 16; ++rep) {
    int idx = rep * 256 + tid;
    int r = idx >> 6, c = idx & 63;
    out[(size_t)(tb * 64 + r) * R + rb * 64 + c] = tile[c][r];
  }
}

// ---------------- bf16 GEMM, B^T input (round-4 version, proven) ----------
// BM=BN=256, BK=32, 512 thr (8 waves 2Mx4N), 4 LDS buffers (128KB).
// Staging 3 K-tiles ahead; one counted vmcnt(4) + one s_barrier per tile.
// Register frag double-buffer: tile t+1's 12 ds_read_b128 issue before
// tile t's 32-MFMA cluster.
template <typename OutT>
__global__ __launch_bounds__(512, 2) void k_gemm8(const short* __restrict__ A,
                                                  const short* __restrict__ BT,
                                                  OutT* __restrict__ C,
                                                  int M, int N, int K) {
  __shared__ short sA[4][8192];   // [buf][256 rows][32 k], swizzled granules
  __shared__ short sB[4][8192];
  const int tid = threadIdx.x;
  const int wv = tid >> 6, lane = tid & 63;
  const int l16 = lane & 15, lhi = lane >> 4;
  const int wr = wv >> 2, wc = wv & 3;          // wave grid 2M x 4N
  const int bm = blockIdx.x * 256, bn = blockIdx.y * 256;
  const int srow0 = wv * 16 + (lane >> 2);      // staging row within 128-half
  const int sgs = lane & 3;                     // stored granule
  const int NT = K >> 5;

  auto stageA = [&](int kt, int b) {
#pragma unroll
    for (int j = 0; j < 2; ++j) {
      int row = j * 128 + srow0;
      int g = sgs ^ ((row >> 1) & 3);           // logical granule for this slot
      gld_lds16(A + (size_t)(bm + row) * K + kt + g * 8,
                &sA[b][j * 4096 + wv * 512]);   // wave-uniform base + lane*16B
    }
  };
  auto stageB = [&](int kt, int b) {
#pragma unroll
    for (int j = 0; j < 2; ++j) {
      int row = j * 128 + srow0;
      int g = sgs ^ ((row >> 1) & 3);
      gld_lds16(BT + (size_t)(bn + row) * K + kt + g * 8,
                &sB[b][j * 4096 + wv * 512]);
    }
  };

  f32x4 acc[8][4] = {};
  bf16x8 aP[8], bP[4], aQ[8], bQ[4];

#define FRAG_READ(DA, DB, BUF)                                                 \
  {                                                                            \
    const short* bufA_ = sA[(BUF)];                                            \
    const short* bufB_ = sB[(BUF)];                                            \
    _Pragma("unroll") for (int n = 0; n < 4; ++n) {                            \
      int row = wc * 64 + n * 16 + l16;                                        \
      DB[n] = *(const bf16x8*)&bufB_[row * 32 + ((lhi ^ ((row >> 1) & 3)) << 3)]; \
    }                                                                          \
    _Pragma("unroll") for (int m = 0; m < 8; ++m) {                            \
      int row = wr * 128 + m * 16 + l16;                                       \
      DA[m] = *(const bf16x8*)&bufA_[row * 32 + ((lhi ^ ((row >> 1) & 3)) << 3)]; \
    }                                                                          \
  }

#define TILE_BODY(T, CA, CB, NA, NB)                                           \
  {                                                                            \
    const int t_ = (T);                                                        \
    if (t_ + 1 < NT) FRAG_READ(NA, NB, (t_ + 1) & 3);                          \
    if (t_ + 3 < NT) {                                                         \
      stageA((t_ + 3) * 32, (t_ + 3) & 3);                                     \
      stageB((t_ + 3) * 32, (t_ + 3) & 3);                                     \
    }                                                                          \
    __builtin_amdgcn_sched_barrier(0);                                         \
    if (t_ + 3 < NT) {                                                         \
      asm volatile("s_waitcnt vmcnt(4)" ::: "memory");                         \
    } else {                                                                   \
      asm volatile("s_waitcnt vmcnt(0)" ::: "memory");                         \
    }                                                                          \
    __builtin_amdgcn_sched_barrier(0);                                         \
    __builtin_amdgcn_s_setprio(1);                                             \
    _Pragma("unroll") for (int m = 0; m < 8; ++m)                              \
        _Pragma("unroll") for (int n = 0; n < 4; ++n)                          \
            acc[m][n] = __builtin_amdgcn_mfma_f32_16x16x32_bf16(               \
                CA[m], CB[n], acc[m][n], 0, 0, 0);                             \
    __builtin_amdgcn_s_setprio(0);                                             \
    __builtin_amdgcn_sched_barrier(0);                                         \
    __builtin_amdgcn_s_barrier();                                              \
    __builtin_amdgcn_sched_barrier(0);                                         \
  }

  // prologue: stage tiles 0,1,2; publish 0 and 1; preload tile-0 frags
  stageA(0, 0); stageB(0, 0);
  stageA(32, 1); stageB(32, 1);
  stageA(64, 2); stageB(64, 2);
  asm volatile("s_waitcnt vmcnt(8)" ::: "memory");   // tile 0 landed
  __builtin_amdgcn_s_barrier();
  FRAG_READ(aP, bP, 0);
  asm volatile("s_waitcnt vmcnt(4)" ::: "memory");   // tile 1 landed
  __builtin_amdgcn_s_barrier();
  __builtin_amdgcn_sched_barrier(0);

  for (int t = 0; t < NT; t += 2) {      // NT even (K % 64 == 0)
    TILE_BODY(t, aP, bP, aQ, bQ);
    TILE_BODY(t + 1, aQ, bQ, aP, bP);
  }
#undef FRAG_READ
#undef TILE_BODY

#pragma unroll
  for (int m = 0; m < 8; ++m) {
#pragma unroll
    for (int n = 0; n < 4; ++n) {
      int col = bn + wc * 64 + n * 16 + l16;
#pragma unroll
      for (int r = 0; r < 4; ++r) {
        int row = bm + wr * 128 + m * 16 + lhi * 4 + r;
        if constexpr (sizeof(OutT) == 2)
          C[(size_t)row * N + col] = (OutT)f2bf(acc[m][n][r]);
        else
          C[(size_t)row * N + col] = acc[m][n][r];
      }
    }
  }
}

// ---------------- RoPE: qkv -> Qr,Kr in [B,H,T,128] bf16 ----------------
// Q additionally pre-scaled by 1/sqrt(hd) * log2(e) so QK^T lands in exp2 domain.
__global__ __launch_bounds__(256) void k_rope(const short* __restrict__ qkv,
                                              const float* __restrict__ cosb,
                                              const float* __restrict__ sinb,
                                              short* __restrict__ Qr,
                                              short* __restrict__ Kr) {
  const float kC = 0.08838834764831845f * 1.44269504088896340f;
  int gid = blockIdx.x * 4 + (threadIdx.x >> 6);  // (b*T+t)*H + h
  int lane = threadIdx.x & 63;                    // pair index 0..63
  int h = gid & 15;
  int bt = gid >> 4;
  int t = bt & 2047;
  int b = bt >> 11;
  float c = cosb[t * 64 + lane];
  float s = sinb[t * 64 + lane];
  size_t qidx = (size_t)bt * 6144 + h * 128 + 2 * lane;
  size_t oidx = ((size_t)(b * 16 + h) * 2048 + t) * 128 + 2 * lane;
  unsigned int qp = *reinterpret_cast<const unsigned int*>(qkv + qidx);
  {
    float x1 = bf2f(qp & 0xffffu), x2 = bf2f(qp >> 16);
    unsigned int o = (unsigned)f2bf((x1 * c - x2 * s) * kC) |
                     ((unsigned)f2bf((x1 * s + x2 * c) * kC) << 16);
    *reinterpret_cast<unsigned int*>(Qr + oidx) = o;
  }
  unsigned int kp = *reinterpret_cast<const unsigned int*>(qkv + qidx + 2048);
  {
    float x1 = bf2f(kp & 0xffffu), x2 = bf2f(kp >> 16);
    unsigned int o = (unsigned)f2bf(x1 * c - x2 * s) |
                     ((unsigned)f2bf(x1 * s + x2 * c) << 16);
    *reinterpret_cast<unsigned int*>(Kr + oidx) = o;
  }
}

// ---------------- V transpose: qkv v-part -> VT [B,H,128,T] bf16 ----------------
__global__ __launch_bounds__(256) void k_vtrans(const short* __restrict__ qkv,
                                                short* __restrict__ VT) {
  __shared__ short tile[64][66];
  int bh = blockIdx.x;
  int t0 = blockIdx.y * 64;
  int d0 = blockIdx.z * 64;
  int b = bh >> 4, h = bh & 15;
  int tid = threadIdx.x;
#pragma unroll
  for (int rep = 0; rep < 16; ++rep) {
    int idx = rep * 256 + tid;
    int r = idx >> 6, c = idx & 63;
    tile[r][c] = qkv[(size_t)(b * 2048 + t0 + r) * 6144 + 4096 + h * 128 + d0 + c];
  }
  __syncthreads();
#pragma unroll
  for (int rep = 0; rep < 16; ++rep) {
    int idx = rep * 256 + tid;
    int r = idx >> 6, c = idx & 63;
    VT[(size_t)(bh * 128 + d0 + r) * 2048 + t0 + c] = tile[c][r];
  }
}

// ---------------- causal flash attention (v3: 32 q-rows/wave) ----------------
// block = (bh, pair of 128-row q-tiles qt and 15-qt) -> 36 KV iters/block.
// 4 waves x 32 q-rows (2 x 16-row frags), KVBLK=64. Each kf/vb LDS read now
// feeds TWO MFMAs (one per q-frag) -> LDS read traffic per unit work halved.
// Double-buffered K/V staging; row-sum via ones-MFMA; defer-max (THR=8).
__global__ __launch_bounds__(256) void k_attn(const short* __restrict__ Qr,
                                              const short* __restrict__ Kr,
                                              const short* __restrict__ VT,
                                              short* __restrict__ Y) {
  __shared__ short sK[2][64 * 128];    // 32 KB
  __shared__ short sVT[2][128 * 64];   // 32 KB
  __shared__ short sP[4][32 * 64];     // 16 KB
  const int tid = threadIdx.x, wv = tid >> 6, lane = tid & 63;
  const int l8r = lane >> 3, l8c = lane & 7, l16 = lane & 15, lhi = lane >> 4;
  const int bid = blockIdx.x;
  const int pair = bid & 7, bh = bid >> 3;
  const size_t base = (size_t)bh * 2048 * 128;
  const int b = bh >> 4, h = bh & 15;

  const short ob = (short)0x3F80;                   // bf16 1.0
  const bf16x8 ones = {ob, ob, ob, ob, ob, ob, ob, ob};

  auto stage = [&](int kv0, int buf) {
#pragma unroll
    for (int rr = 0; rr < 4; ++rr) {
      int ch = rr * 4 + wv;
      {                                    // sK: row stride 256B, chunk = 4 rows
        int row = ch * 4 + lhi;
        int wch = l16 ^ (row & 7);         // inverse-swizzled source chunk
        gld_lds16(Kr + base + (size_t)(kv0 + row) * 128 + wch * 8,
                  &sK[buf][ch * 512]);
      }
      {                                    // sVT: row stride 128B, chunk = 8 rows
        int drow = ch * 8 + l8r;
        int wch = l8c ^ (drow & 7);
        gld_lds16(VT + base + (size_t)drow * 2048 + kv0 + wch * 8,
                  &sVT[buf][ch * 512]);
      }
    }
  };

  for (int half = 0; half < 2; ++half) {
    const int qt = half ? 15 - pair : pair;
    const int q0 = qt * 128;               // 128-row q-tile
    const int nt = 2 * qt + 2;

    bf16x8 qf[2][4];
#pragma unroll
    for (int v = 0; v < 2; ++v) {
      const int qrow = q0 + wv * 32 + v * 16 + l16;
#pragma unroll
      for (int ks = 0; ks < 4; ++ks)
        qf[v][ks] = *reinterpret_cast<const bf16x8*>(
            Qr + base + (size_t)qrow * 128 + ks * 32 + lhi * 8);
    }

    f32x4 acc_o[2][8] = {};
    f32x4 acc_l[2] = {};
    float m_run[2][4];
#pragma unroll
    for (int v = 0; v < 2; ++v)
#pragma unroll
      for (int r = 0; r < 4; ++r) m_run[v][r] = -1e30f;

    stage(0, 0);
    __syncthreads();

    for (int it = 0; it < nt; ++it) {
      const int cur = it & 1;
      if (it + 1 < nt) stage((it + 1) * 64, cur ^ 1);   // prefetch next tile

      // S = Q K^T (exp2 domain; kC folded into Q). kf shared by both q-frags.
      f32x4 sacc[2][4] = {};
#pragma unroll
      for (int cf = 0; cf < 4; ++cf) {
        int krow = cf * 16 + l16;
#pragma unroll
        for (int ks = 0; ks < 4; ++ks) {
          int e = krow * 128 + ks * 32 + lhi * 8;
          bf16x8 kf = *reinterpret_cast<const bf16x8*>(
              &sK[cur][e ^ ((krow & 7) << 3)]);
          sacc[0][cf] = __builtin_amdgcn_mfma_f32_16x16x32_bf16(qf[0][ks], kf,
                                                                sacc[0][cf], 0, 0, 0);
          sacc[1][cf] = __builtin_amdgcn_mfma_f32_16x16x32_bf16(qf[1][ks], kf,
                                                                sacc[1][cf], 0, 0, 0);
        }
      }

      if (it >= nt - 2) {                  // causal mask (last two KV tiles)
        const int rel = it * 64 - q0;      // kv0 - q0 (0 or 64)
#pragma unroll
        for (int v = 0; v < 2; ++v)
#pragma unroll
          for (int cf = 0; cf < 4; ++cf) {
            int col = rel + cf * 16 + l16;
#pragma unroll
            for (int r = 0; r < 4; ++r)
              if (col > wv * 32 + v * 16 + lhi * 4 + r) sacc[v][cf][r] = -3e38f;
          }
      }

      // defer-max: slow path only when a row max grows past THR=8 (exp2-units)
      bool exceed = false;
#pragma unroll
      for (int v = 0; v < 2; ++v)
#pragma unroll
        for (int cf = 0; cf < 4; ++cf)
#pragma unroll
          for (int r = 0; r < 4; ++r)
            exceed |= (sacc[v][cf][r] > m_run[v][r] + 8.f);

      if (__any(exceed)) {
#pragma unroll
        for (int v = 0; v < 2; ++v) {
          float resc[4];
#pragma unroll
          for (int r = 0; r < 4; ++r) {
            float mx = fmaxf(fmaxf(sacc[v][0][r], sacc[v][1][r]),
                             fmaxf(sacc[v][2][r], sacc[v][3][r]));
            mx = fmaxf(mx, __shfl_xor(mx, 1));
            mx = fmaxf(mx, __shfl_xor(mx, 2));
            mx = fmaxf(mx, __shfl_xor(mx, 4));
            mx = fmaxf(mx, __shfl_xor(mx, 8));
            float mnew = fmaxf(m_run[v][r], mx);
            resc[r] = exp2f(m_run[v][r] - mnew);
            m_run[v][r] = mnew;
          }
#pragma unroll
          for (int df = 0; df < 8; ++df)
#pragma unroll
            for (int r = 0; r < 4; ++r) acc_o[v][df][r] *= resc[r];
#pragma unroll
          for (int r = 0; r < 4; ++r) acc_l[v][r] *= resc[r];
        }
      }

      // P = exp2(S - m), bf16, into per-wave swizzled LDS (A-frag reshape)
#pragma unroll
      for (int v = 0; v < 2; ++v)
#pragma unroll
        for (int cf = 0; cf < 4; ++cf)
#pragma unroll
          for (int r = 0; r < 4; ++r) {
            float p = exp2f(sacc[v][cf][r] - m_run[v][r]);
            int prow = v * 16 + lhi * 4 + r;
            int e = prow * 64 + cf * 16 + l16;
            sP[wv][e ^ ((prow & 7) << 3)] = (short)f2bf(p);
          }

      // O += P V ; l += P * ones.  vb shared by both q-frags.
#pragma unroll
      for (int kk = 0; kk < 2; ++kk) {
        bf16x8 pa[2];
#pragma unroll
        for (int v = 0; v < 2; ++v) {
          int prow = v * 16 + l16;
          int e = prow * 64 + kk * 32 + lhi * 8;
          pa[v] = *reinterpret_cast<const bf16x8*>(
              &sP[wv][e ^ ((prow & 7) << 3)]);
          acc_l[v] = __builtin_amdgcn_mfma_f32_16x16x32_bf16(pa[v], ones,
                                                             acc_l[v], 0, 0, 0);
        }
#pragma unroll
        for (int df = 0; df < 8; ++df) {
          int vrow = df * 16 + l16;
          int ev = vrow * 64 + kk * 32 + lhi * 8;
          bf16x8 vb = *reinterpret_cast<const bf16x8*>(
              &sVT[cur][ev ^ ((vrow & 7) << 3)]);
          acc_o[0][df] = __builtin_amdgcn_mfma_f32_16x16x32_bf16(pa[0], vb,
                                                                 acc_o[0][df], 0, 0, 0);
          acc_o[1][df] = __builtin_amdgcn_mfma_f32_16x16x32_bf16(pa[1], vb,
                                                                 acc_o[1][df], 0, 0, 0);
        }
      }
      __syncthreads();   // drains prefetch vmcnt + protects LDS buffers
    }

#pragma unroll
    for (int v = 0; v < 2; ++v) {
      float inv[4];
#pragma unroll
      for (int r = 0; r < 4; ++r) inv[r] = 1.f / acc_l[v][r];
#pragma unroll
      for (int df = 0; df < 8; ++df) {
        int col = h * 128 + df * 16 + l16;
#pragma unroll
        for (int r = 0; r < 4; ++r) {
          int row = q0 + wv * 32 + v * 16 + lhi * 4 + r;
          Y[((size_t)b * 2048 + row) * 2048 + col] =
              (short)f2bf(acc_o[v][df][r] * inv[r]);
        }
      }
    }
  }
}

// ---------------- launch ----------------
extern "C" void kernel_launch(void* const* d_in, const int* in_sizes, int n_in,
                              void* d_out, int out_size, void* d_ws, size_t ws_size,
                              hipStream_t stream) {
  const float* x        = (const float*)d_in[0];
  const float* w_attn   = (const float*)d_in[1];
  const float* w_proj   = (const float*)d_in[2];
  const float* rope_cos = (const float*)d_in[3];
  const float* rope_sin = (const float*)d_in[4];

  char* ws = (char*)d_ws;                     // 256 MiB total layout
  short* xbf    = (short*)(ws);               // 33.5 MB  [8192][2048]
  short* wattnT = (short*)(ws + 33554432ull); // 25.2 MB  [6144][2048]
  short* wprojT = (short*)(ws + 58720256ull); //  8.4 MB  [2048][2048]
  short* qkv    = (short*)(ws + 67108864ull); // 100.7 MB [8192][6144]
  short* Y      = qkv;                        // alias dead q-region (33.5 MB)
  short* Qr     = (short*)(ws + 167772160ull);// 33.5 MB  [B,H,T,128]
  short* Kr     = (short*)(ws + 201326592ull);// 33.5 MB  [B,H,T,128]
  short* VT     = (short*)(ws + 234881024ull);// 33.5 MB  [B,H,128,T]

  k_conv<<<16384, 256, 0, stream>>>(x, xbf, 4194304);
  k_transpose<<<3072, 256, 0, stream>>>(w_attn, wattnT, 2048, 6144);
  k_transpose<<<1024, 256, 0, stream>>>(w_proj, wprojT, 2048, 2048);
  k_gemm8<short><<<dim3(32, 24), 512, 0, stream>>>(xbf, wattnT, qkv,
                                                   8192, 6144, 2048);
  k_rope<<<32768, 256, 0, stream>>>(qkv, rope_cos, rope_sin, Qr, Kr);
  k_vtrans<<<dim3(64, 32, 2), 256, 0, stream>>>(qkv, VT);
  k_attn<<<512, 256, 0, stream>>>(Qr, Kr, VT, Y);
  k_gemm8<float><<<dim3(32, 8), 512, 0, stream>>>(Y, wprojT, (float*)d_out,
                                                  8192, 2048, 2048);
}

// Round 7
// 473.089 us; speedup vs baseline: 1.1642x; 1.1028x over previous
//
#include <hip/hip_runtime.h>
#include <cstdint>
#include <cstddef>

#define DEVI __device__ __forceinline__

typedef __attribute__((ext_vector_type(8))) short bf16x8;
typedef __attribute__((ext_vector_type(4))) float f32x4;

DEVI unsigned short f2bf(float f) {
  unsigned int u = __float_as_uint(f);
  u += 0x7fffu + ((u >> 16) & 1u);   // RNE
  return (unsigned short)(u >> 16);
}
DEVI float bf2f(unsigned int us) { return __uint_as_float(us << 16); }

DEVI void gld_lds16(const void* g, void* l) {
  __builtin_amdgcn_global_load_lds(
      (const __attribute__((address_space(1))) void*)g,
      (__attribute__((address_space(3))) void*)l, 16, 0, 0);
}

// ---------------- fp32 -> bf16 elementwise ----------------
__global__ __launch_bounds__(256) void k_conv(const float* __restrict__ in,
                                              short* __restrict__ out, int n4) {
  int i = blockIdx.x * 256 + threadIdx.x;
  if (i >= n4) return;
  float4 v = reinterpret_cast<const float4*>(in)[i];
  uint2 o;
  o.x = (unsigned)f2bf(v.x) | ((unsigned)f2bf(v.y) << 16);
  o.y = (unsigned)f2bf(v.z) | ((unsigned)f2bf(v.w) << 16);
  reinterpret_cast<uint2*>(out)[i] = o;
}

// ---------------- fp32 [R][C] -> bf16 [C][R] transpose ----------------
__global__ __launch_bounds__(256) void k_transpose(const float* __restrict__ in,
                                                   short* __restrict__ out,
                                                   int R, int Cc) {
  __shared__ short tile[64][66];
  int tcols = Cc >> 6;
  int tb = blockIdx.x % tcols;
  int rb = blockIdx.x / tcols;
  int tid = threadIdx.x;
#pragma unroll
  for (int rep = 0; rep < 16; ++rep) {
    int idx = rep * 256 + tid;
    int r = idx >> 6, c = idx & 63;
    tile[r][c] = (short)f2bf(in[(size_t)(rb * 64 + r) * Cc + tb * 64 + c]);
  }
  __syncthreads();
#pragma unroll
  for (int rep = 0; rep < 16; ++rep) {
    int idx = rep * 256 + tid;
    int r = idx >> 6, c = idx & 63;
    out[(size_t)(tb * 64 + r) * R + rb * 64 + c] = tile[c][r];
  }
}

// ---------------- bf16 GEMM, B^T input (round-4 pipeline, proven) --------
// BM=BN=256, BK=32, 512 thr (8 waves 2Mx4N), 4 LDS buffers (128KB).
// Staging 3 K-tiles ahead; one counted vmcnt(4) + one s_barrier per tile.
// Register frag double-buffer: tile t+1's 12 ds_read_b128 issue before
// tile t's 32-MFMA cluster.
// MODE 1: plain fp32 C output.  MODE 2: fused QKV epilogue -> RoPE'd Q,K
// ([B,H,T,128] bf16, Q pre-scaled by 1/sqrt(hd)*log2e) + transposed V
// ([B,H,128,T] bf16). Each 256-col block lies wholly in q, k, or v.
template <int MODE, typename OutT>
__global__ __launch_bounds__(512, 2) void k_gemm8(const short* __restrict__ A,
                                                  const short* __restrict__ BT,
                                                  OutT* __restrict__ C,
                                                  int M, int N, int K,
                                                  const float* __restrict__ cosb,
                                                  const float* __restrict__ sinb,
                                                  short* __restrict__ Qr,
                                                  short* __restrict__ Kr,
                                                  short* __restrict__ VT) {
  __shared__ short sA[4][8192];   // [buf][256 rows][32 k], swizzled granules
  __shared__ short sB[4][8192];
  const int tid = threadIdx.x;
  const int wv = tid >> 6, lane = tid & 63;
  const int l16 = lane & 15, lhi = lane >> 4;
  const int wr = wv >> 2, wc = wv & 3;          // wave grid 2M x 4N
  const int bm = blockIdx.x * 256, bn = blockIdx.y * 256;
  const int srow0 = wv * 16 + (lane >> 2);      // staging row within 128-half
  const int sgs = lane & 3;                     // stored granule
  const int NT = K >> 5;

  auto stageA = [&](int kt, int b) {
#pragma unroll
    for (int j = 0; j < 2; ++j) {
      int row = j * 128 + srow0;
      int g = sgs ^ ((row >> 1) & 3);           // logical granule for this slot
      gld_lds16(A + (size_t)(bm + row) * K + kt + g * 8,
                &sA[b][j * 4096 + wv * 512]);   // wave-uniform base + lane*16B
    }
  };
  auto stageB = [&](int kt, int b) {
#pragma unroll
    for (int j = 0; j < 2; ++j) {
      int row = j * 128 + srow0;
      int g = sgs ^ ((row >> 1) & 3);
      gld_lds16(BT + (size_t)(bn + row) * K + kt + g * 8,
                &sB[b][j * 4096 + wv * 512]);
    }
  };

  f32x4 acc[8][4] = {};
  bf16x8 aP[8], bP[4], aQ[8], bQ[4];

#define FRAG_READ(DA, DB, BUF)                                                 \
  {                                                                            \
    const short* bufA_ = sA[(BUF)];                                            \
    const short* bufB_ = sB[(BUF)];                                            \
    _Pragma("unroll") for (int n = 0; n < 4; ++n) {                            \
      int row = wc * 64 + n * 16 + l16;                                        \
      DB[n] = *(const bf16x8*)&bufB_[row * 32 + ((lhi ^ ((row >> 1) & 3)) << 3)]; \
    }                                                                          \
    _Pragma("unroll") for (int m = 0; m < 8; ++m) {                            \
      int row = wr * 128 + m * 16 + l16;                                       \
      DA[m] = *(const bf16x8*)&bufA_[row * 32 + ((lhi ^ ((row >> 1) & 3)) << 3)]; \
    }                                                                          \
  }

#define TILE_BODY(T, CA, CB, NA, NB)                                           \
  {                                                                            \
    const int t_ = (T);                                                        \
    if (t_ + 1 < NT) FRAG_READ(NA, NB, (t_ + 1) & 3);                          \
    if (t_ + 3 < NT) {                                                         \
      stageA((t_ + 3) * 32, (t_ + 3) & 3);                                     \
      stageB((t_ + 3) * 32, (t_ + 3) & 3);                                     \
    }                                                                          \
    __builtin_amdgcn_sched_barrier(0);                                         \
    if (t_ + 3 < NT) {                                                         \
      asm volatile("s_waitcnt vmcnt(4)" ::: "memory");                         \
    } else {                                                                   \
      asm volatile("s_waitcnt vmcnt(0)" ::: "memory");                         \
    }                                                                          \
    __builtin_amdgcn_sched_barrier(0);                                         \
    __builtin_amdgcn_s_setprio(1);                                             \
    _Pragma("unroll") for (int m = 0; m < 8; ++m)                              \
        _Pragma("unroll") for (int n = 0; n < 4; ++n)                          \
            acc[m][n] = __builtin_amdgcn_mfma_f32_16x16x32_bf16(               \
                CA[m], CB[n], acc[m][n], 0, 0, 0);                             \
    __builtin_amdgcn_s_setprio(0);                                             \
    __builtin_amdgcn_sched_barrier(0);                                         \
    __builtin_amdgcn_s_barrier();                                              \
    __builtin_amdgcn_sched_barrier(0);                                         \
  }

  // prologue: stage tiles 0,1,2; publish 0 and 1; preload tile-0 frags
  stageA(0, 0); stageB(0, 0);
  stageA(32, 1); stageB(32, 1);
  stageA(64, 2); stageB(64, 2);
  asm volatile("s_waitcnt vmcnt(8)" ::: "memory");   // tile 0 landed
  __builtin_amdgcn_s_barrier();
  FRAG_READ(aP, bP, 0);
  asm volatile("s_waitcnt vmcnt(4)" ::: "memory");   // tile 1 landed
  __builtin_amdgcn_s_barrier();
  __builtin_amdgcn_sched_barrier(0);

  for (int t = 0; t < NT; t += 2) {      // NT even (K % 64 == 0)
    TILE_BODY(t, aP, bP, aQ, bQ);
    TILE_BODY(t + 1, aQ, bQ, aP, bP);
  }
#undef FRAG_READ
#undef TILE_BODY

  if constexpr (MODE == 1) {
#pragma unroll
    for (int m = 0; m < 8; ++m) {
#pragma unroll
      for (int n = 0; n < 4; ++n) {
        int col = bn + wc * 64 + n * 16 + l16;
#pragma unroll
        for (int r = 0; r < 4; ++r) {
          int row = bm + wr * 128 + m * 16 + lhi * 4 + r;
          C[(size_t)row * N + col] = acc[m][n][r];
        }
      }
    }
  } else {
    // MODE 2: fused QKV epilogue. part: 0=q, 1=k, 2=v (block-uniform).
    const int part = bn >> 11;
    const float kC = 0.08838834764831845f * 1.44269504088896340f;
    if (part < 2) {
      const float qs = (part == 0) ? kC : 1.0f;
      short* dst = (part == 0) ? Qr : Kr;
#pragma unroll
      for (int m = 0; m < 8; ++m) {
#pragma unroll
        for (int n = 0; n < 4; ++n) {
          int colm = (bn & 2047) + wc * 64 + n * 16 + l16;  // 0..2047
          int h = colm >> 7, d = colm & 127;
          int p = d >> 1;
          bool ev = (d & 1) == 0;
#pragma unroll
          for (int r = 0; r < 4; ++r) {
            int row = bm + wr * 128 + m * 16 + lhi * 4 + r;
            int b = row >> 11, t = row & 2047;
            float c = cosb[t * 64 + p];
            float s = sinb[t * 64 + p];
            float x = acc[m][n][r];
            float xp = __shfl_xor(x, 1);                    // partner d^1
            float y = ev ? (x * c - xp * s) : (xp * s + x * c);
            dst[((size_t)(b * 16 + h) * 2048 + t) * 128 + d] =
                (short)f2bf(y * qs);
          }
        }
      }
    } else {
#pragma unroll
      for (int m = 0; m < 8; ++m) {
#pragma unroll
        for (int n = 0; n < 4; ++n) {
          int colm = (bn & 2047) + wc * 64 + n * 16 + l16;
          int h = colm >> 7, d = colm & 127;
#pragma unroll
          for (int r = 0; r < 4; ++r) {
            int row = bm + wr * 128 + m * 16 + lhi * 4 + r;
            int b = row >> 11, t = row & 2047;
            VT[((size_t)(b * 16 + h) * 128 + d) * 2048 + t] =
                (short)f2bf(acc[m][n][r]);
          }
        }
      }
    }
  }
}

// ---------------- causal flash attention (round-2 v2, proven) ----------------
// block = (bh, pair): q-tiles qt=pair and qt=31-pair -> 33 KV iters/block.
// 4 waves x 16 q-rows, KVBLK=64, double-buffered K/V via global_load_lds.
// Row-sum of P via MFMA with all-ones B; defer-max (THR=8, exp2 domain).
__global__ __launch_bounds__(256) void k_attn(const short* __restrict__ Qr,
                                              const short* __restrict__ Kr,
                                              const short* __restrict__ VT,
                                              short* __restrict__ Y) {
  __shared__ short sK[2][64 * 128];
  __shared__ short sVT[2][128 * 64];
  __shared__ short sP[4][16 * 64];
  const int tid = threadIdx.x, wv = tid >> 6, lane = tid & 63;
  const int l8r = lane >> 3, l8c = lane & 7, l16 = lane & 15, lhi = lane >> 4;
  const int bid = blockIdx.x;
  const int pair = bid & 15, bh = bid >> 4;
  const size_t base = (size_t)bh * 2048 * 128;
  const int b = bh >> 4, h = bh & 15;

  const short ob = (short)0x3F80;                   // bf16 1.0
  const bf16x8 ones = {ob, ob, ob, ob, ob, ob, ob, ob};

  auto stage = [&](int kv0, int buf) {
#pragma unroll
    for (int rr = 0; rr < 4; ++rr) {
      int ch = rr * 4 + wv;
      {                                    // sK: row stride 256B, chunk = 4 rows
        int row = ch * 4 + lhi;
        int wch = l16 ^ (row & 7);         // inverse-swizzled source chunk
        gld_lds16(Kr + base + (size_t)(kv0 + row) * 128 + wch * 8,
                  &sK[buf][ch * 512]);
      }
      {                                    // sVT: row stride 128B, chunk = 8 rows
        int drow = ch * 8 + l8r;
        int wch = l8c ^ (drow & 7);
        gld_lds16(VT + base + (size_t)drow * 2048 + kv0 + wch * 8,
                  &sVT[buf][ch * 512]);
      }
    }
  };

  for (int half = 0; half < 2; ++half) {
    const int qt = half ? 31 - pair : pair;
    const int q0 = qt * 64;
    const int nt = qt + 1;

    bf16x8 qf[4];
    const int qrow = q0 + wv * 16 + l16;
#pragma unroll
    for (int ks = 0; ks < 4; ++ks)
      qf[ks] = *reinterpret_cast<const bf16x8*>(Qr + base + (size_t)qrow * 128 +
                                                ks * 32 + lhi * 8);

    f32x4 acc_o[8] = {};
    f32x4 acc_l = {};
    float m_run[4];
#pragma unroll
    for (int r = 0; r < 4; ++r) m_run[r] = -1e30f;

    stage(0, 0);
    __syncthreads();

    for (int it = 0; it < nt; ++it) {
      const int cur = it & 1;
      if (it + 1 < nt) stage((it + 1) * 64, cur ^ 1);   // prefetch next tile

      // S = Q K^T  (scores already in exp2 domain: kC folded into Q)
      f32x4 sacc[4] = {};
#pragma unroll
      for (int cf = 0; cf < 4; ++cf) {
        int krow = cf * 16 + l16;
#pragma unroll
        for (int ks = 0; ks < 4; ++ks) {
          int e = krow * 128 + ks * 32 + lhi * 8;
          bf16x8 kf = *reinterpret_cast<const bf16x8*>(
              &sK[cur][e ^ ((krow & 7) << 3)]);
          sacc[cf] = __builtin_amdgcn_mfma_f32_16x16x32_bf16(qf[ks], kf,
                                                             sacc[cf], 0, 0, 0);
        }
      }

      if (it == nt - 1) {                  // causal mask on diagonal tile
#pragma unroll
        for (int cf = 0; cf < 4; ++cf) {
          int col = cf * 16 + l16;
#pragma unroll
          for (int r = 0; r < 4; ++r)
            if (col > wv * 16 + lhi * 4 + r) sacc[cf][r] = -3e38f;
        }
      }

      // defer-max: slow path only when a row max grows past THR=8 (exp2-units)
      bool exceed = false;
#pragma unroll
      for (int cf = 0; cf < 4; ++cf)
#pragma unroll
        for (int r = 0; r < 4; ++r)
          exceed |= (sacc[cf][r] > m_run[r] + 8.f);

      if (__any(exceed)) {
        float resc[4];
#pragma unroll
        for (int r = 0; r < 4; ++r) {
          float mx = fmaxf(fmaxf(sacc[0][r], sacc[1][r]),
                           fmaxf(sacc[2][r], sacc[3][r]));
          mx = fmaxf(mx, __shfl_xor(mx, 1));
          mx = fmaxf(mx, __shfl_xor(mx, 2));
          mx = fmaxf(mx, __shfl_xor(mx, 4));
          mx = fmaxf(mx, __shfl_xor(mx, 8));
          float mnew = fmaxf(m_run[r], mx);
          resc[r] = exp2f(m_run[r] - mnew);
          m_run[r] = mnew;
        }
#pragma unroll
        for (int df = 0; df < 8; ++df)
#pragma unroll
          for (int r = 0; r < 4; ++r) acc_o[df][r] *= resc[r];
#pragma unroll
        for (int r = 0; r < 4; ++r) acc_l[r] *= resc[r];
      }

      // P = exp2(S - m), bf16, into per-wave swizzled LDS (A-frag reshape)
#pragma unroll
      for (int cf = 0; cf < 4; ++cf)
#pragma unroll
        for (int r = 0; r < 4; ++r) {
          float p = exp2f(sacc[cf][r] - m_run[r]);
          int prow = lhi * 4 + r;
          int e = prow * 64 + cf * 16 + l16;
          sP[wv][e ^ ((prow & 7) << 3)] = (short)f2bf(p);
        }

      // O += P V ; l += P * ones  (row-sum via MFMA, no shuffle reduce)
#pragma unroll
      for (int kk = 0; kk < 2; ++kk) {
        int e = l16 * 64 + kk * 32 + lhi * 8;
        bf16x8 pa = *reinterpret_cast<const bf16x8*>(
            &sP[wv][e ^ ((l16 & 7) << 3)]);
        acc_l = __builtin_amdgcn_mfma_f32_16x16x32_bf16(pa, ones, acc_l, 0, 0, 0);
#pragma unroll
        for (int df = 0; df < 8; ++df) {
          int vrow = df * 16 + l16;
          int ev = vrow * 64 + kk * 32 + lhi * 8;
          bf16x8 vb = *reinterpret_cast<const bf16x8*>(
              &sVT[cur][ev ^ ((vrow & 7) << 3)]);
          acc_o[df] = __builtin_amdgcn_mfma_f32_16x16x32_bf16(pa, vb,
                                                              acc_o[df], 0, 0, 0);
        }
      }
      __syncthreads();   // drains prefetch vmcnt + protects LDS buffers
    }

    float inv[4];
#pragma unroll
    for (int r = 0; r < 4; ++r) inv[r] = 1.f / acc_l[r];
#pragma unroll
    for (int df = 0; df < 8; ++df) {
      int col = h * 128 + df * 16 + l16;
#pragma unroll
      for (int r = 0; r < 4; ++r) {
        int row = q0 + wv * 16 + lhi * 4 + r;
        Y[((size_t)b * 2048 + row) * 2048 + col] =
            (short)f2bf(acc_o[df][r] * inv[r]);
      }
    }
  }
}

// ---------------- launch ----------------
extern "C" void kernel_launch(void* const* d_in, const int* in_sizes, int n_in,
                              void* d_out, int out_size, void* d_ws, size_t ws_size,
                              hipStream_t stream) {
  const float* x        = (const float*)d_in[0];
  const float* w_attn   = (const float*)d_in[1];
  const float* w_proj   = (const float*)d_in[2];
  const float* rope_cos = (const float*)d_in[3];
  const float* rope_sin = (const float*)d_in[4];

  char* ws = (char*)d_ws;                     // 256 MiB total layout
  short* xbf    = (short*)(ws);               // 33.5 MB  [8192][2048]
  short* wattnT = (short*)(ws + 33554432ull); // 25.2 MB  [6144][2048]
  short* wprojT = (short*)(ws + 58720256ull); //  8.4 MB  [2048][2048]
  short* Y      = (short*)(ws + 67108864ull); // 33.5 MB  [8192][2048]
  short* Qr     = (short*)(ws + 167772160ull);// 33.5 MB  [B,H,T,128]
  short* Kr     = (short*)(ws + 201326592ull);// 33.5 MB  [B,H,T,128]
  short* VT     = (short*)(ws + 234881024ull);// 33.5 MB  [B,H,128,T]

  k_conv<<<16384, 256, 0, stream>>>(x, xbf, 4194304);
  k_transpose<<<3072, 256, 0, stream>>>(w_attn, wattnT, 2048, 6144);
  k_transpose<<<1024, 256, 0, stream>>>(w_proj, wprojT, 2048, 2048);
  k_gemm8<2, short><<<dim3(32, 24), 512, 0, stream>>>(
      xbf, wattnT, (short*)nullptr, 8192, 6144, 2048,
      rope_cos, rope_sin, Qr, Kr, VT);
  k_attn<<<1024, 256, 0, stream>>>(Qr, Kr, VT, Y);
  k_gemm8<1, float><<<dim3(32, 8), 512, 0, stream>>>(
      Y, wprojT, (float*)d_out, 8192, 2048, 2048,
      nullptr, nullptr, nullptr, nullptr, nullptr);
}